// Round 10
// baseline (132.324 us; speedup 1.0000x reference)
//
#include <hip/hip_runtime.h>
#include <hip/hip_bf16.h>
#include <math.h>

#define BB   32
#define NN   64
#define NGG  100
#define NBB  128
#define NFF  256
#define NITER 3
#define KPAD 128

typedef _Float16 f16x8 __attribute__((ext_vector_type(8)));
typedef _Float16 f16x4 __attribute__((ext_vector_type(4)));
typedef float    f32x4 __attribute__((ext_vector_type(4)));

static __device__ __forceinline__ float fast_exp2(float x) {
    float r; asm("v_exp_f32 %0, %1" : "=v"(r) : "v"(x)); return r;
}
static __device__ __forceinline__ float fast_rcp(float x) {
    float r; asm("v_rcp_f32 %0, %1" : "=v"(r) : "v"(x)); return r;
}
// tanh(x) = 1 - 2/(e^{2x}+1). Saturates correctly for large |x|.
static __device__ __forceinline__ float fast_tanh(float x) {
    float p = fast_exp2(x * 2.8853900817779268f);
    return 1.0f - 2.0f * fast_rcp(p + 1.0f);
}

// ---------------- merged prep: embed + WcF + WfF + WiF + W1F ----------------
#define EMB_N (BB * NN * NBB)      // 262144
#define WCF_N (NFF * KPAD)         // 32768
#define WFF_N (NBB * NFF)          // 32768
#define WIF_N (NBB * NFF)          // 32768
#define W1F_N (NBB * 64)           // 8192
#define PREP_TOTAL (EMB_N + WCF_N + WFF_N + WIF_N + W1F_N)
#define PREP_GRID (PREP_TOTAL / 256)
__global__ void prep_kernel(const int* __restrict__ Z, const float* __restrict__ W_emb,
                            const float* __restrict__ Wc, const float* __restrict__ Wf,
                            const float* __restrict__ Wi, const float* __restrict__ W1,
                            float* __restrict__ X, _Float16* __restrict__ WcF,
                            _Float16* __restrict__ WfF, _Float16* __restrict__ WiF,
                            _Float16* __restrict__ W1F) {
    int idx = blockIdx.x * 256 + threadIdx.x;
    if (idx < EMB_N) {
        int bn = idx >> 7, t = idx & 127;
        X[idx] = W_emb[Z[bn] * NBB + t];
        return;
    }
    idx -= EMB_N;
    if (idx < WCF_N) {
        int e = idx & 7, lane = (idx >> 3) & 63, ks = (idx >> 9) & 3, ct = (idx >> 11) & 3, w = idx >> 13;
        int l15 = lane & 15, kg = lane >> 4;
        int f = w * 64 + ct * 16 + l15;
        int k = ks * 32 + kg * 8 + e;
        WcF[idx] = (k < NGG) ? (_Float16)Wc[(size_t)k * NFF + f] : (_Float16)0.f;
        return;
    }
    idx -= WCF_N;
    if (idx < WFF_N) {
        int e = idx & 7, lane = (idx >> 3) & 63, ks = (idx >> 9) & 7, ct = (idx >> 12) & 1, w = idx >> 13;
        int l15 = lane & 15, kg = lane >> 4;
        int o = w * 32 + ct * 16 + l15;
        int k = ks * 32 + kg * 8 + e;
        WfF[idx] = (_Float16)Wf[(size_t)k * NBB + o];
        return;
    }
    idx -= WFF_N;
    if (idx < WIF_N) {
        int e = idx & 7, lane = (idx >> 3) & 63, ks = (idx >> 9) & 3, ct16 = idx >> 11;
        int l15 = lane & 15, kg = lane >> 4;
        int f = ct16 * 16 + l15;
        int k = ks * 32 + kg * 8 + e;
        WiF[idx] = (_Float16)Wi[(size_t)k * NFF + f];
        return;
    }
    idx -= WIF_N;
    if (idx < W1F_N) {
        int e = idx & 7, lane = (idx >> 3) & 63, ks = (idx >> 9) & 3, ct16 = idx >> 11;
        int l15 = lane & 15, kg = lane >> 4;
        int o = ct16 * 16 + l15;
        int k = ks * 32 + kg * 8 + e;
        W1F[idx] = (_Float16)W1[(size_t)k * 64 + o];
    }
}

// old row-major transposed layouts (fused fallback only)
__global__ void transpose_pad_kernel(const float* __restrict__ src, _Float16* __restrict__ dst,
                                     int K, int Kpad, int NC) {
    int idx = blockIdx.x * 256 + threadIdx.x;
    if (idx >= NC * Kpad) return;
    int c = idx / Kpad, k = idx - c * Kpad;
    dst[idx] = (k < K) ? (_Float16)src[(size_t)k * NC + c] : (_Float16)0.f;
}

// ---------------- stage fp32 row-major [64][<=128] -> LDS f16 [64][128] XOR-swizzled ----------------
static __device__ __forceinline__ void stage_C(const float* Crow_base, _Float16* Cs, int t) {
    const int r = t >> 2, q = t & 3;
    const float* Crow = Crow_base + (size_t)r * NGG;
    const int sw = (r & 7) << 3;
    #pragma unroll
    for (int m = 0; m < 8; ++m) {
        const int k = q * 32 + m * 4;
        f16x4 h = {0.f, 0.f, 0.f, 0.f};
        if (k < NGG) {
            float4 v = *(const float4*)(Crow + k);
            h[0] = (_Float16)v.x; h[1] = (_Float16)v.y;
            h[2] = (_Float16)v.z; h[3] = (_Float16)v.w;
        }
        *(f16x4*)&Cs[r * KPAD + (k ^ sw)] = h;
    }
}
static __device__ __forceinline__ void stage_X(const float* Xrow_base, _Float16* Xs, int t) {
    const int r = t >> 2, q = t & 3;
    const float* Xrow = Xrow_base + (size_t)r * NBB;
    const int sw = (r & 7) << 3;
    #pragma unroll
    for (int m = 0; m < 8; ++m) {
        const int k = q * 32 + m * 4;
        float4 v = *(const float4*)(Xrow + k);
        f16x4 h;
        h[0] = (_Float16)v.x; h[1] = (_Float16)v.y;
        h[2] = (_Float16)v.z; h[3] = (_Float16)v.w;
        *(f16x4*)&Xs[r * KPAD + (k ^ sw)] = h;
    }
}

// ---------------- fc body: fCF frags of (C[bi,j,:]@Wc + bc) ----------------
static __device__ __forceinline__ void fc_body(
    int bi_, int t, _Float16* Cs,
    const int* __restrict__ Z, const float* __restrict__ C,
    const _Float16* __restrict__ WcF, const float* __restrict__ bc,
    _Float16* __restrict__ fCF)
{
    const int b = bi_ >> 6, i = bi_ & 63;
    if (Z[b * NN + i] == 0) return;   // slice never read downstream

    const int wave = t >> 6, lane = t & 63;
    const int l15 = lane & 15, kg = lane >> 4;

    stage_C(C + (size_t)bi_ * NN * NGG, Cs, t);

    f16x8 aw[4][4];
    float4 bcq[4];
    #pragma unroll
    for (int ct = 0; ct < 4; ++ct) {
        #pragma unroll
        for (int ks = 0; ks < 4; ++ks)
            aw[ct][ks] = *(const f16x8*)&WcF[(size_t)(((wave * 4 + ct) * 4 + ks) * 64 + lane) * 8];
        bcq[ct] = *(const float4*)&bc[wave * 64 + ct * 16 + kg * 4];
    }
    __syncthreads();

    #pragma unroll
    for (int jt = 0; jt < 4; ++jt) {
        const int j = jt * 16 + l15;
        const int sw = (l15 & 7) << 3;
        f16x8 bfr[4];
        #pragma unroll
        for (int ks = 0; ks < 4; ++ks)
            bfr[ks] = *(const f16x8*)&Cs[j * KPAD + ((ks * 32 + kg * 8) ^ sw)];
        #pragma unroll
        for (int ct = 0; ct < 4; ++ct) {
            f32x4 acc = {bcq[ct].x, bcq[ct].y, bcq[ct].z, bcq[ct].w};
            #pragma unroll
            for (int ks = 0; ks < 4; ++ks)
                acc = __builtin_amdgcn_mfma_f32_16x16x32_f16(aw[ct][ks], bfr[ks], acc, 0, 0, 0);
            const int u = ct * 16 + kg * 4;       // f within wave's 64
            const int ksf = wave * 2 + (u >> 5);
            const int kgf = (u >> 3) & 3;
            const int e0 = u & 4;
            f16x4 o;
            o[0] = (_Float16)acc[0]; o[1] = (_Float16)acc[1];
            o[2] = (_Float16)acc[2]; o[3] = (_Float16)acc[3];
            size_t off = ((size_t)(bi_ * 32 + jt * 8 + ksf) * 64 + (kgf * 16 + l15)) * 8 + e0;
            *(f16x4*)&fCF[off] = o;
        }
    }
}

// ---------------- fx body (MFMA): fXF frags of (X[b]@Wi + bi), Z-masked ----------------
// Writes result to fXF; for Z==0 rows ALSO zeros fXFz (the ping-pong partner never
// otherwise initialized for dead rows — ws is poisoned 0xAA).
static __device__ __forceinline__ void fxm_body(
    int b, int fq, int t, _Float16* Xs,
    const float* __restrict__ X, const _Float16* __restrict__ WiF,
    const float* __restrict__ bi, const int* __restrict__ Z,
    _Float16* __restrict__ fXF, _Float16* __restrict__ fXFz)
{
    const int wave = t >> 6, lane = t & 63;
    const int l15 = lane & 15, kg = lane >> 4;
    const int ct16 = fq * 4 + wave;

    stage_X(X + (size_t)b * NN * NBB, Xs, t);

    f16x8 aw[4];
    #pragma unroll
    for (int ks = 0; ks < 4; ++ks)
        aw[ks] = *(const f16x8*)&WiF[(size_t)((ct16 * 4 + ks) * 64 + lane) * 8];
    float4 biq = *(const float4*)&bi[ct16 * 16 + kg * 4];
    __syncthreads();

    f32x4 acc[4];
    #pragma unroll
    for (int jt = 0; jt < 4; ++jt) acc[jt] = (f32x4){biq.x, biq.y, biq.z, biq.w};

    #pragma unroll
    for (int ks = 0; ks < 4; ++ks) {
        #pragma unroll
        for (int jt = 0; jt < 4; ++jt) {
            const int j = jt * 16 + l15;
            const int sw = (l15 & 7) << 3;
            f16x8 bfr = *(const f16x8*)&Xs[j * KPAD + ((ks * 32 + kg * 8) ^ sw)];
            acc[jt] = __builtin_amdgcn_mfma_f32_16x16x32_f16(aw[ks], bfr, acc[jt], 0, 0, 0);
        }
    }

    const int u_g = ct16 * 16 + kg * 4;
    const int ks_t = u_g >> 5, kg_t = (u_g >> 3) & 3, e0 = u_g & 4;
    #pragma unroll
    for (int jt = 0; jt < 4; ++jt) {
        const int j = jt * 16 + l15;
        const int zj = Z[b * NN + j];
        f16x4 o = {0.f, 0.f, 0.f, 0.f};
        size_t off = ((size_t)(b * 32 + jt * 8 + ks_t) * 64 + (kg_t * 16 + l15)) * 8 + e0;
        if (zj > 0) {
            o[0] = (_Float16)acc[jt][0]; o[1] = (_Float16)acc[jt][1];
            o[2] = (_Float16)acc[jt][2]; o[3] = (_Float16)acc[jt][3];
        } else {
            *(f16x4*)&fXFz[off] = o;   // zero the partner buffer for dead rows
        }
        *(f16x4*)&fXF[off] = o;
    }
}

#define FXM_GRID (BB * 4)   // 128

__global__ __launch_bounds__(256) void fxm_kernel(
    const float* __restrict__ X, const _Float16* __restrict__ WiF,
    const float* __restrict__ bi, const int* __restrict__ Z,
    _Float16* __restrict__ fXF)
{
    __shared__ __align__(16) _Float16 Xs[NN * KPAD];
    fxm_body(blockIdx.x >> 2, blockIdx.x & 3, threadIdx.x, Xs, X, WiF, bi, Z, fXF, fXF);
}

// ---------------- merged fc + fx(pass 1): independent work, disjoint block ranges ----------------
__global__ __launch_bounds__(256, 3) void fcfx_kernel(
    const int* __restrict__ Z, const float* __restrict__ C,
    const _Float16* __restrict__ WcF, const float* __restrict__ bc,
    _Float16* __restrict__ fCF,
    const float* __restrict__ X, const _Float16* __restrict__ WiF,
    const float* __restrict__ bi, _Float16* __restrict__ fXF,
    _Float16* __restrict__ fXFz)
{
    __shared__ __align__(16) _Float16 S[NN * KPAD];   // 16 KB, shared by both roles
    if (blockIdx.x < FXM_GRID)
        fxm_body(blockIdx.x >> 2, blockIdx.x & 3, threadIdx.x, S, X, WiF, bi, Z, fXF, fXFz);
    else
        fc_body(blockIdx.x - FXM_GRID, threadIdx.x, S, Z, C, WcF, bc, fCF);
}

// ---------------- per-pass: fV=fCF⊙fXin ; pre=fV@Wf ; X += Σ_{j!=i} tanh ----------------
// TAIL=1: after updating X[b,i], compute fXout[b,i,:] = X_new@Wi + bi for the NEXT pass.
// RACE-FREE: fXin (read by all blocks) and fXout (written, one row per block) are
// DISTINCT ping-pong buffers; Z==0 rows of both were zeroed by fcfx.
template<int TAIL>
__global__ __launch_bounds__(256) void interact_lite(
    const int* __restrict__ Z, const _Float16* __restrict__ fCF,
    const _Float16* __restrict__ WfF, const _Float16* __restrict__ fXin,
    _Float16* __restrict__ fXout,
    float* __restrict__ X, const float* __restrict__ Wi,
    const float* __restrict__ bi)
{
    __shared__ float xrow[NBB];
    const int bi_ = blockIdx.x;
    const int b = bi_ >> 6, i = bi_ & 63;
    if (Z[b * NN + i] == 0) return;   // block-uniform; row's fX buffers stay 0 forever

    const int t = threadIdx.x;
    const int wave = t >> 6, lane = t & 63;
    const int kg = lane >> 4;

    f16x8 bwf[2][8];
    #pragma unroll
    for (int ct = 0; ct < 2; ++ct)
        #pragma unroll
        for (int ks = 0; ks < 8; ++ks)
            bwf[ct][ks] = *(const f16x8*)&WfF[(size_t)(((wave * 2 + ct) * 8 + ks) * 64 + lane) * 8];

    const size_t cbase = (size_t)bi_ * 32;
    const size_t xbase = (size_t)b * 32;

    f32x4 a[4][2];
    #pragma unroll
    for (int jt = 0; jt < 4; ++jt) {
        a[jt][0] = (f32x4){0.f, 0.f, 0.f, 0.f};
        a[jt][1] = (f32x4){0.f, 0.f, 0.f, 0.f};
    }

    #pragma unroll
    for (int ks = 0; ks < 8; ++ks) {
        #pragma unroll
        for (int jt = 0; jt < 4; ++jt) {
            f16x8 fc = *(const f16x8*)&fCF[((cbase + jt * 8 + ks) * 64 + lane) * 8];
            f16x8 fx = *(const f16x8*)&fXin[((xbase + jt * 8 + ks) * 64 + lane) * 8];
            f16x8 av = fc * fx;                    // v_pk_mul_f16
            a[jt][0] = __builtin_amdgcn_mfma_f32_16x16x32_f16(av, bwf[0][ks], a[jt][0], 0, 0, 0);
            a[jt][1] = __builtin_amdgcn_mfma_f32_16x16x32_f16(av, bwf[1][ks], a[jt][1], 0, 0, 0);
        }
    }

    float vsum0 = 0.f, vsum1 = 0.f;
    #pragma unroll
    for (int jt = 0; jt < 4; ++jt) {
        #pragma unroll
        for (int reg = 0; reg < 4; ++reg) {
            int j2 = jt * 16 + kg * 4 + reg;
            if (j2 != i) {
                vsum0 += fast_tanh(a[jt][0][reg]);
                vsum1 += fast_tanh(a[jt][1][reg]);
            }
        }
    }
    vsum0 += __shfl_xor(vsum0, 16); vsum0 += __shfl_xor(vsum0, 32);
    vsum1 += __shfl_xor(vsum1, 16); vsum1 += __shfl_xor(vsum1, 32);
    if (lane < 16) {
        float* Xp = X + (size_t)bi_ * NBB + wave * 32 + lane;
        float n0 = Xp[0]  + vsum0;
        float n1 = Xp[16] + vsum1;
        Xp[0]  = n0;
        Xp[16] = n1;
        if (TAIL) {
            xrow[wave * 32 + lane]      = n0;
            xrow[wave * 32 + lane + 16] = n1;
        }
    }

    if (TAIL) {
        __syncthreads();
        // GEMV: thread t computes f=t of fX_next[b,i,:] (xrow broadcast, Wi coalesced, L2-hot)
        float acc0 = bi[t], acc1 = 0.f;
        #pragma unroll 8
        for (int k = 0; k < NBB; k += 2) {
            acc0 += xrow[k]     * Wi[(size_t)k * NFF + t];
            acc1 += xrow[k + 1] * Wi[(size_t)(k + 1) * NFF + t];
        }
        float acc = acc0 + acc1;
        // fXF fragment slot for (j=i, f=t)
        const int jt = i >> 4, l15r = i & 15;
        const int ksx = t >> 5, kg2 = (t >> 3) & 3, e = t & 7;
        fXout[((size_t)(b * 32 + jt * 8 + ksx) * 64 + (kg2 * 16 + l15r)) * 8 + e] = (_Float16)acc;
    }
}

// ---------------- fused fallback (old layouts) ----------------
__global__ __launch_bounds__(256, 3) void interact_fused(
    const int* __restrict__ Z, const float* __restrict__ C,
    const _Float16* __restrict__ WcT, const float* __restrict__ bc,
    const _Float16* __restrict__ WfT, const _Float16* __restrict__ fXF,
    float* __restrict__ X)
{
    __shared__ __align__(16) _Float16 Cs[NN * KPAD];
    __shared__ __align__(16) _Float16 fVs[NN * NFF];

    const int bi_ = blockIdx.x;
    const int b = bi_ >> 6, i = bi_ & 63;
    if (Z[b * NN + i] == 0) return;

    const int t = threadIdx.x;
    const int wave = t >> 6, lane = t & 63;
    const int l15 = lane & 15, kg = lane >> 4;

    stage_C(C + (size_t)bi_ * NN * NGG, Cs, t);

    f16x8 aw[4][4];
    float4 bcq[4];
    #pragma unroll
    for (int ct = 0; ct < 4; ++ct) {
        #pragma unroll
        for (int ks = 0; ks < 4; ++ks)
            aw[ct][ks] = *(const f16x8*)&WcT[(size_t)(wave * 64 + ct * 16 + l15) * KPAD + ks * 32 + kg * 8];
        bcq[ct] = *(const float4*)&bc[wave * 64 + ct * 16 + kg * 4];
    }
    __syncthreads();

    #pragma unroll
    for (int jt = 0; jt < 4; ++jt) {
        const int j = jt * 16 + l15;
        const int sw = (l15 & 7) << 3;
        f16x8 bfr[4];
        #pragma unroll
        for (int ks = 0; ks < 4; ++ks)
            bfr[ks] = *(const f16x8*)&Cs[j * KPAD + ((ks * 32 + kg * 8) ^ sw)];
        #pragma unroll
        for (int ct = 0; ct < 4; ++ct) {
            f32x4 acc = {bcq[ct].x, bcq[ct].y, bcq[ct].z, bcq[ct].w};
            #pragma unroll
            for (int ks = 0; ks < 4; ++ks)
                acc = __builtin_amdgcn_mfma_f32_16x16x32_f16(aw[ct][ks], bfr[ks], acc, 0, 0, 0);
            const int u = ct * 16 + kg * 4;
            const int ksf = wave * 2 + (u >> 5);
            const int kgf = (u >> 3) & 3;
            const int e0 = u & 4;
            f16x4 fx4 = *(const f16x4*)&fXF[((size_t)(b * 32 + jt * 8 + ksf) * 64 + (kgf * 16 + l15)) * 8 + e0];
            const int f0 = wave * 64 + u;
            f16x4 o;
            o[0] = (_Float16)(acc[0] * (float)fx4[0]);
            o[1] = (_Float16)(acc[1] * (float)fx4[1]);
            o[2] = (_Float16)(acc[2] * (float)fx4[2]);
            o[3] = (_Float16)(acc[3] * (float)fx4[3]);
            *(f16x4*)&fVs[j * NFF + (f0 ^ ((j & 7) << 3))] = o;
        }
    }
    __syncthreads();

    f16x8 bwf[2][8];
    #pragma unroll
    for (int ct = 0; ct < 2; ++ct)
        #pragma unroll
        for (int ks = 0; ks < 8; ++ks)
            bwf[ct][ks] = *(const f16x8*)&WfT[(size_t)(wave * 32 + ct * 16 + l15) * NFF + ks * 32 + kg * 8];

    float vsum0 = 0.f, vsum1 = 0.f;
    #pragma unroll
    for (int jt = 0; jt < 4; ++jt) {
        const int r = jt * 16 + l15;
        const int sw = (l15 & 7) << 3;
        f32x4 a0 = {0.f, 0.f, 0.f, 0.f}, a1 = {0.f, 0.f, 0.f, 0.f};
        #pragma unroll
        for (int ks = 0; ks < 8; ++ks) {
            f16x8 av = *(const f16x8*)&fVs[r * NFF + ((ks * 32 + kg * 8) ^ sw)];
            a0 = __builtin_amdgcn_mfma_f32_16x16x32_f16(av, bwf[0][ks], a0, 0, 0, 0);
            a1 = __builtin_amdgcn_mfma_f32_16x16x32_f16(av, bwf[1][ks], a1, 0, 0, 0);
        }
        #pragma unroll
        for (int reg = 0; reg < 4; ++reg) {
            int j2 = jt * 16 + kg * 4 + reg;
            if (j2 != i) {
                vsum0 += fast_tanh(a0[reg]);
                vsum1 += fast_tanh(a1[reg]);
            }
        }
    }
    vsum0 += __shfl_xor(vsum0, 16); vsum0 += __shfl_xor(vsum0, 32);
    vsum1 += __shfl_xor(vsum1, 16); vsum1 += __shfl_xor(vsum1, 32);
    if (lane < 16) {
        float* Xp = X + (size_t)bi_ * NBB + wave * 32 + lane;
        Xp[0]  += vsum0;
        Xp[16] += vsum1;
    }
}

// ---------------- readout (MFMA, one block per b, writes y directly) ----------------
__global__ __launch_bounds__(256) void readout_kernel(
    const int* __restrict__ Z, const float* __restrict__ X,
    const _Float16* __restrict__ W1F, const float* __restrict__ b1,
    const float* __restrict__ W2, const float* __restrict__ b2,
    float* __restrict__ y)
{
    __shared__ __align__(16) _Float16 Xs[NN * KPAD];   // 16 KB
    __shared__ float part[4][NN];                      // 1 KB
    const int b = blockIdx.x, t = threadIdx.x;
    const int wave = t >> 6, lane = t & 63;
    const int l15 = lane & 15, kg = lane >> 4;

    stage_X(X + (size_t)b * NN * NBB, Xs, t);

    f16x8 aw[4];
    #pragma unroll
    for (int ks = 0; ks < 4; ++ks)
        aw[ks] = *(const f16x8*)&W1F[(size_t)((wave * 4 + ks) * 64 + lane) * 8];
    float4 b1q = *(const float4*)&b1[wave * 16 + kg * 4];
    float4 w2q = *(const float4*)&W2[wave * 16 + kg * 4];
    __syncthreads();

    f32x4 acc[4];
    #pragma unroll
    for (int jt = 0; jt < 4; ++jt) acc[jt] = (f32x4){b1q.x, b1q.y, b1q.z, b1q.w};

    #pragma unroll
    for (int ks = 0; ks < 4; ++ks) {
        #pragma unroll
        for (int jt = 0; jt < 4; ++jt) {
            const int j = jt * 16 + l15;
            const int sw = (l15 & 7) << 3;
            f16x8 bfr = *(const f16x8*)&Xs[j * KPAD + ((ks * 32 + kg * 8) ^ sw)];
            acc[jt] = __builtin_amdgcn_mfma_f32_16x16x32_f16(aw[ks], bfr, acc[jt], 0, 0, 0);
        }
    }

    #pragma unroll
    for (int jt = 0; jt < 4; ++jt) {
        float s = fast_tanh(acc[jt][0]) * w2q.x + fast_tanh(acc[jt][1]) * w2q.y
                + fast_tanh(acc[jt][2]) * w2q.z + fast_tanh(acc[jt][3]) * w2q.w;
        s += __shfl_xor(s, 16); s += __shfl_xor(s, 32);
        if (lane < 16) part[wave][jt * 16 + lane] = s;
    }
    __syncthreads();

    if (t < NN) {
        float s = part[0][t] + part[1][t] + part[2][t] + part[3][t] + b2[0];
        float v = (Z[b * NN + t] > 0) ? s : 0.f;
        #pragma unroll
        for (int off = 32; off > 0; off >>= 1) v += __shfl_down(v, off);
        if (t == 0) y[b] = v;
    }
}

extern "C" void kernel_launch(void* const* d_in, const int* in_sizes, int n_in,
                              void* d_out, int out_size, void* d_ws, size_t ws_size,
                              hipStream_t stream) {
    (void)in_sizes; (void)n_in; (void)out_size;
    const int*   Z    = (const int*)d_in[0];
    const float* C    = (const float*)d_in[1];
    const float* Wemb = (const float*)d_in[2];
    const float* Wc   = (const float*)d_in[3];
    const float* bc   = (const float*)d_in[4];
    const float* Wi   = (const float*)d_in[5];
    const float* bi   = (const float*)d_in[6];
    const float* Wf   = (const float*)d_in[7];
    const float* W1   = (const float*)d_in[8];
    const float* b1   = (const float*)d_in[9];
    const float* W2   = (const float*)d_in[10];
    const float* b2   = (const float*)d_in[11];
    float* y = (float*)d_out;

    // ws: X f32 | fXF_A | fXF_B | WcF | WfF | WiF | W1F | WcT | WfT | fCF(67MB)
    char* p = (char*)d_ws;
    float*    X    = (float*)p;      p += (size_t)BB * NN * NBB * 4;
    _Float16* fXFa = (_Float16*)p;   p += (size_t)BB * NN * NFF * 2;
    _Float16* fXFb = (_Float16*)p;   p += (size_t)BB * NN * NFF * 2;
    _Float16* WcF  = (_Float16*)p;   p += (size_t)WCF_N * 2;
    _Float16* WfF  = (_Float16*)p;   p += (size_t)WFF_N * 2;
    _Float16* WiF  = (_Float16*)p;   p += (size_t)WIF_N * 2;
    _Float16* W1F  = (_Float16*)p;   p += (size_t)W1F_N * 2;
    _Float16* WcT  = (_Float16*)p;   p += (size_t)NFF * KPAD * 2;
    _Float16* WfT  = (_Float16*)p;   p += (size_t)NBB * NFF * 2;
    size_t base = (size_t)(p - (char*)d_ws);
    size_t fcf_bytes = (size_t)BB * NN * NN * NFF * 2;   // 67 MB
    bool split = (ws_size >= base + fcf_bytes);          // constant per session
    _Float16* fCF = (_Float16*)p;

    prep_kernel<<<PREP_GRID, 256, 0, stream>>>(Z, Wemb, Wc, Wf, Wi, W1, X, WcF, WfF, WiF, W1F);

    if (split) {
        // pass 1 inputs: fc + fx merged; fx writes A, zeros dead rows of B too
        fcfx_kernel<<<FXM_GRID + BB * NN, 256, 0, stream>>>(Z, C, WcF, bc, fCF, X, WiF, bi, fXFa, fXFb);
        // ping-pong: read A -> write B, read B -> write A, read A (no tail)
        interact_lite<1><<<BB * NN, 256, 0, stream>>>(Z, fCF, WfF, fXFa, fXFb, X, Wi, bi);
        interact_lite<1><<<BB * NN, 256, 0, stream>>>(Z, fCF, WfF, fXFb, fXFa, X, Wi, bi);
        interact_lite<0><<<BB * NN, 256, 0, stream>>>(Z, fCF, WfF, fXFa, fXFb, X, Wi, bi);
    } else {
        transpose_pad_kernel<<<(NFF * KPAD) / 256, 256, 0, stream>>>(Wc, WcT, NGG, KPAD, NFF);
        transpose_pad_kernel<<<(NBB * NFF) / 256, 256, 0, stream>>>(Wf, WfT, NFF, NFF, NBB);
        for (int it = 0; it < NITER; ++it) {
            fxm_kernel<<<FXM_GRID, 256, 0, stream>>>(X, WiF, bi, Z, fXFa);
            interact_fused<<<BB * NN, 256, 0, stream>>>(Z, C, WcT, bc, WfT, fXFa, X);
        }
    }
    readout_kernel<<<BB, 256, 0, stream>>>(Z, X, W1F, b1, W2, b2, y);
}

// Round 11
// 124.802 us; speedup vs baseline: 1.0603x; 1.0603x over previous
//
#include <hip/hip_runtime.h>
#include <hip/hip_bf16.h>
#include <math.h>

#define BB   32
#define NN   64
#define NGG  100
#define NBB  128
#define NFF  256
#define NITER 3
#define KPAD 128

typedef _Float16 f16x8 __attribute__((ext_vector_type(8)));
typedef _Float16 f16x4 __attribute__((ext_vector_type(4)));
typedef float    f32x4 __attribute__((ext_vector_type(4)));

static __device__ __forceinline__ float fast_exp2(float x) {
    float r; asm("v_exp_f32 %0, %1" : "=v"(r) : "v"(x)); return r;
}
static __device__ __forceinline__ float fast_rcp(float x) {
    float r; asm("v_rcp_f32 %0, %1" : "=v"(r) : "v"(x)); return r;
}
// tanh(x) = 1 - 2/(e^{2x}+1). Saturates correctly for large |x|.
static __device__ __forceinline__ float fast_tanh(float x) {
    float p = fast_exp2(x * 2.8853900817779268f);
    return 1.0f - 2.0f * fast_rcp(p + 1.0f);
}

// ---------------- prep: weight fragments only (embed eliminated) ----------------
// WcF[w4][ct4][ks4][lane64][e8]: lane(l15,kg) holds Wc[k=ks*32+kg*8+e][f=w*64+ct*16+l15]
// WfF[w4][ct2][ks8][lane64][e8]: Wf[k][o=w*32+ct*16+l15]
// WiF[ct16_16][ks4][lane64][e8]: Wi[k][f=ct16*16+l15]
// W1F[ct16_4][ks4][lane64][e8]:  W1[k][o=ct16*16+l15]
#define WCF_N (NFF * KPAD)         // 32768
#define WFF_N (NBB * NFF)          // 32768
#define WIF_N (NBB * NFF)          // 32768
#define W1F_N (NBB * 64)           // 8192
#define PREP_TOTAL (WCF_N + WFF_N + WIF_N + W1F_N)
#define PREP_GRID (PREP_TOTAL / 256)
__global__ void prep_kernel(const float* __restrict__ Wc, const float* __restrict__ Wf,
                            const float* __restrict__ Wi, const float* __restrict__ W1,
                            _Float16* __restrict__ WcF, _Float16* __restrict__ WfF,
                            _Float16* __restrict__ WiF, _Float16* __restrict__ W1F) {
    int idx = blockIdx.x * 256 + threadIdx.x;
    if (idx < WCF_N) {
        int e = idx & 7, lane = (idx >> 3) & 63, ks = (idx >> 9) & 3, ct = (idx >> 11) & 3, w = idx >> 13;
        int l15 = lane & 15, kg = lane >> 4;
        int f = w * 64 + ct * 16 + l15;
        int k = ks * 32 + kg * 8 + e;
        WcF[idx] = (k < NGG) ? (_Float16)Wc[(size_t)k * NFF + f] : (_Float16)0.f;
        return;
    }
    idx -= WCF_N;
    if (idx < WFF_N) {
        int e = idx & 7, lane = (idx >> 3) & 63, ks = (idx >> 9) & 7, ct = (idx >> 12) & 1, w = idx >> 13;
        int l15 = lane & 15, kg = lane >> 4;
        int o = w * 32 + ct * 16 + l15;
        int k = ks * 32 + kg * 8 + e;
        WfF[idx] = (_Float16)Wf[(size_t)k * NBB + o];
        return;
    }
    idx -= WFF_N;
    if (idx < WIF_N) {
        int e = idx & 7, lane = (idx >> 3) & 63, ks = (idx >> 9) & 3, ct16 = idx >> 11;
        int l15 = lane & 15, kg = lane >> 4;
        int f = ct16 * 16 + l15;
        int k = ks * 32 + kg * 8 + e;
        WiF[idx] = (_Float16)Wi[(size_t)k * NFF + f];
        return;
    }
    idx -= WIF_N;
    if (idx < W1F_N) {
        int e = idx & 7, lane = (idx >> 3) & 63, ks = (idx >> 9) & 3, ct16 = idx >> 11;
        int l15 = lane & 15, kg = lane >> 4;
        int o = ct16 * 16 + l15;
        int k = ks * 32 + kg * 8 + e;
        W1F[idx] = (_Float16)W1[(size_t)k * 64 + o];
    }
}

// ---------------- embed (fallback path only) ----------------
__global__ void embed_kernel(const int* __restrict__ Z, const float* __restrict__ W_emb,
                             float* __restrict__ X) {
    int bn = blockIdx.x, t = threadIdx.x;
    X[bn * NBB + t] = W_emb[Z[bn] * NBB + t];
}

// old row-major transposed layouts (fused fallback only)
__global__ void transpose_pad_kernel(const float* __restrict__ src, _Float16* __restrict__ dst,
                                     int K, int Kpad, int NC) {
    int idx = blockIdx.x * 256 + threadIdx.x;
    if (idx >= NC * Kpad) return;
    int c = idx / Kpad, k = idx - c * Kpad;
    dst[idx] = (k < K) ? (_Float16)src[(size_t)k * NC + c] : (_Float16)0.f;
}

// ---------------- stage fp32 row-major [64][<=128] -> LDS f16 [64][128] XOR-swizzled ----------------
static __device__ __forceinline__ void stage_C(const float* Crow_base, _Float16* Cs, int t) {
    const int r = t >> 2, q = t & 3;
    const float* Crow = Crow_base + (size_t)r * NGG;
    const int sw = (r & 7) << 3;
    #pragma unroll
    for (int m = 0; m < 8; ++m) {
        const int k = q * 32 + m * 4;
        f16x4 h = {0.f, 0.f, 0.f, 0.f};
        if (k < NGG) {
            float4 v = *(const float4*)(Crow + k);
            h[0] = (_Float16)v.x; h[1] = (_Float16)v.y;
            h[2] = (_Float16)v.z; h[3] = (_Float16)v.w;
        }
        *(f16x4*)&Cs[r * KPAD + (k ^ sw)] = h;
    }
}
// FIRST=1: row r sourced from W_emb[Z[b,r]] (embed fused); else from X[b,r]
template<int FIRST>
static __device__ __forceinline__ void stage_Xrow(const float* X, const int* Z,
                                                  const float* W_emb, int b,
                                                  _Float16* Xs, int t) {
    const int r = t >> 2, q = t & 3;
    const float* Xrow = FIRST ? (W_emb + (size_t)Z[b * NN + r] * NBB)
                              : (X + ((size_t)b * NN + r) * NBB);
    const int sw = (r & 7) << 3;
    #pragma unroll
    for (int m = 0; m < 8; ++m) {
        const int k = q * 32 + m * 4;
        float4 v = *(const float4*)(Xrow + k);
        f16x4 h;
        h[0] = (_Float16)v.x; h[1] = (_Float16)v.y;
        h[2] = (_Float16)v.z; h[3] = (_Float16)v.w;
        *(f16x4*)&Xs[r * KPAD + (k ^ sw)] = h;
    }
}

// ---------------- fc body: fCF frags of (C[bi,j,:]@Wc + bc) ----------------
static __device__ __forceinline__ void fc_body(
    int bi_, int t, _Float16* Cs,
    const int* __restrict__ Z, const float* __restrict__ C,
    const _Float16* __restrict__ WcF, const float* __restrict__ bc,
    _Float16* __restrict__ fCF)
{
    const int b = bi_ >> 6, i = bi_ & 63;
    if (Z[b * NN + i] == 0) return;   // slice never read downstream

    const int wave = t >> 6, lane = t & 63;
    const int l15 = lane & 15, kg = lane >> 4;

    stage_C(C + (size_t)bi_ * NN * NGG, Cs, t);

    f16x8 aw[4][4];
    float4 bcq[4];
    #pragma unroll
    for (int ct = 0; ct < 4; ++ct) {
        #pragma unroll
        for (int ks = 0; ks < 4; ++ks)
            aw[ct][ks] = *(const f16x8*)&WcF[(size_t)(((wave * 4 + ct) * 4 + ks) * 64 + lane) * 8];
        bcq[ct] = *(const float4*)&bc[wave * 64 + ct * 16 + kg * 4];
    }
    __syncthreads();

    #pragma unroll
    for (int jt = 0; jt < 4; ++jt) {
        const int j = jt * 16 + l15;
        const int sw = (l15 & 7) << 3;
        f16x8 bfr[4];
        #pragma unroll
        for (int ks = 0; ks < 4; ++ks)
            bfr[ks] = *(const f16x8*)&Cs[j * KPAD + ((ks * 32 + kg * 8) ^ sw)];
        #pragma unroll
        for (int ct = 0; ct < 4; ++ct) {
            f32x4 acc = {bcq[ct].x, bcq[ct].y, bcq[ct].z, bcq[ct].w};
            #pragma unroll
            for (int ks = 0; ks < 4; ++ks)
                acc = __builtin_amdgcn_mfma_f32_16x16x32_f16(aw[ct][ks], bfr[ks], acc, 0, 0, 0);
            const int u = ct * 16 + kg * 4;       // f within wave's 64
            const int ksf = wave * 2 + (u >> 5);
            const int kgf = (u >> 3) & 3;
            const int e0 = u & 4;
            f16x4 o;
            o[0] = (_Float16)acc[0]; o[1] = (_Float16)acc[1];
            o[2] = (_Float16)acc[2]; o[3] = (_Float16)acc[3];
            size_t off = ((size_t)(bi_ * 32 + jt * 8 + ksf) * 64 + (kgf * 16 + l15)) * 8 + e0;
            *(f16x4*)&fCF[off] = o;
        }
    }
}

// ---------------- fx body (MFMA): fXF frags of (X[b]@Wi + bi), Z-masked ----------------
template<int FIRST>
static __device__ __forceinline__ void fxm_body(
    int b, int fq, int t, _Float16* Xs,
    const float* __restrict__ X, const _Float16* __restrict__ WiF,
    const float* __restrict__ bi, const int* __restrict__ Z,
    const float* __restrict__ W_emb, _Float16* __restrict__ fXF)
{
    const int wave = t >> 6, lane = t & 63;
    const int l15 = lane & 15, kg = lane >> 4;
    const int ct16 = fq * 4 + wave;

    stage_Xrow<FIRST>(X, Z, W_emb, b, Xs, t);

    f16x8 aw[4];
    #pragma unroll
    for (int ks = 0; ks < 4; ++ks)
        aw[ks] = *(const f16x8*)&WiF[(size_t)((ct16 * 4 + ks) * 64 + lane) * 8];
    float4 biq = *(const float4*)&bi[ct16 * 16 + kg * 4];
    __syncthreads();

    f32x4 acc[4];
    #pragma unroll
    for (int jt = 0; jt < 4; ++jt) acc[jt] = (f32x4){biq.x, biq.y, biq.z, biq.w};

    #pragma unroll
    for (int ks = 0; ks < 4; ++ks) {
        #pragma unroll
        for (int jt = 0; jt < 4; ++jt) {
            const int j = jt * 16 + l15;
            const int sw = (l15 & 7) << 3;
            f16x8 bfr = *(const f16x8*)&Xs[j * KPAD + ((ks * 32 + kg * 8) ^ sw)];
            acc[jt] = __builtin_amdgcn_mfma_f32_16x16x32_f16(aw[ks], bfr, acc[jt], 0, 0, 0);
        }
    }

    const int u_g = ct16 * 16 + kg * 4;
    const int ks_t = u_g >> 5, kg_t = (u_g >> 3) & 3, e0 = u_g & 4;
    #pragma unroll
    for (int jt = 0; jt < 4; ++jt) {
        const int j = jt * 16 + l15;
        const int zj = Z[b * NN + j];
        f16x4 o = {0.f, 0.f, 0.f, 0.f};
        if (zj > 0) {
            o[0] = (_Float16)acc[jt][0]; o[1] = (_Float16)acc[jt][1];
            o[2] = (_Float16)acc[jt][2]; o[3] = (_Float16)acc[jt][3];
        }
        size_t off = ((size_t)(b * 32 + jt * 8 + ks_t) * 64 + (kg_t * 16 + l15)) * 8 + e0;
        *(f16x4*)&fXF[off] = o;
    }
}

#define FXM_GRID (BB * 4)   // 128

__global__ __launch_bounds__(256) void fxm_kernel(
    const float* __restrict__ X, const _Float16* __restrict__ WiF,
    const float* __restrict__ bi, const int* __restrict__ Z,
    _Float16* __restrict__ fXF)
{
    __shared__ __align__(16) _Float16 Xs[NN * KPAD];
    fxm_body<0>(blockIdx.x >> 2, blockIdx.x & 3, threadIdx.x, Xs, X, WiF, bi, Z, (const float*)nullptr, fXF);
}

// fallback pass-1 fx (from W_emb)
__global__ __launch_bounds__(256) void fxm1_kernel(
    const _Float16* __restrict__ WiF, const float* __restrict__ bi,
    const int* __restrict__ Z, const float* __restrict__ W_emb,
    _Float16* __restrict__ fXF)
{
    __shared__ __align__(16) _Float16 Xs[NN * KPAD];
    fxm_body<1>(blockIdx.x >> 2, blockIdx.x & 3, threadIdx.x, Xs, (const float*)nullptr, WiF, bi, Z, W_emb, fXF);
}

// ---------------- merged fc + fx(pass 1, embed-fused): disjoint block ranges ----------------
__global__ __launch_bounds__(256, 3) void fcfx_kernel(
    const int* __restrict__ Z, const float* __restrict__ C,
    const _Float16* __restrict__ WcF, const float* __restrict__ bc,
    _Float16* __restrict__ fCF,
    const _Float16* __restrict__ WiF, const float* __restrict__ bi,
    const float* __restrict__ W_emb, _Float16* __restrict__ fXF)
{
    __shared__ __align__(16) _Float16 S[NN * KPAD];   // 16 KB, shared by both roles
    if (blockIdx.x < FXM_GRID)
        fxm_body<1>(blockIdx.x >> 2, blockIdx.x & 3, threadIdx.x, S, (const float*)nullptr, WiF, bi, Z, W_emb, fXF);
    else
        fc_body(blockIdx.x - FXM_GRID, threadIdx.x, S, Z, C, WcF, bc, fCF);
}

// ---------------- per-pass: fV=fCF⊙fXF ; pre=fV@Wf ; X (=|+=) emb + Σ_{j!=i} tanh ----------------
// FIRST=1: X[b,i] = W_emb[Z[b,i]] + V (embed fused, X never pre-initialized)
template<int FIRST>
__global__ __launch_bounds__(256) void interact_lite(
    const int* __restrict__ Z, const _Float16* __restrict__ fCF,
    const _Float16* __restrict__ WfF, const _Float16* __restrict__ fXF,
    float* __restrict__ X, const float* __restrict__ W_emb)
{
    const int bi_ = blockIdx.x;
    const int b = bi_ >> 6, i = bi_ & 63;
    const int zi = Z[b * NN + i];
    if (zi == 0) return;   // block-uniform; dead rows' X/fXF never read unmasked

    const int t = threadIdx.x;
    const int wave = t >> 6, lane = t & 63;
    const int kg = lane >> 4;

    f16x8 bwf[2][8];
    #pragma unroll
    for (int ct = 0; ct < 2; ++ct)
        #pragma unroll
        for (int ks = 0; ks < 8; ++ks)
            bwf[ct][ks] = *(const f16x8*)&WfF[(size_t)(((wave * 2 + ct) * 8 + ks) * 64 + lane) * 8];

    const size_t cbase = (size_t)bi_ * 32;
    const size_t xbase = (size_t)b * 32;

    f32x4 a[4][2];
    #pragma unroll
    for (int jt = 0; jt < 4; ++jt) {
        a[jt][0] = (f32x4){0.f, 0.f, 0.f, 0.f};
        a[jt][1] = (f32x4){0.f, 0.f, 0.f, 0.f};
    }

    #pragma unroll
    for (int ks = 0; ks < 8; ++ks) {
        #pragma unroll
        for (int jt = 0; jt < 4; ++jt) {
            f16x8 fc = *(const f16x8*)&fCF[((cbase + jt * 8 + ks) * 64 + lane) * 8];
            f16x8 fx = *(const f16x8*)&fXF[((xbase + jt * 8 + ks) * 64 + lane) * 8];
            f16x8 av = fc * fx;                    // v_pk_mul_f16
            a[jt][0] = __builtin_amdgcn_mfma_f32_16x16x32_f16(av, bwf[0][ks], a[jt][0], 0, 0, 0);
            a[jt][1] = __builtin_amdgcn_mfma_f32_16x16x32_f16(av, bwf[1][ks], a[jt][1], 0, 0, 0);
        }
    }

    float vsum0 = 0.f, vsum1 = 0.f;
    #pragma unroll
    for (int jt = 0; jt < 4; ++jt) {
        #pragma unroll
        for (int reg = 0; reg < 4; ++reg) {
            int j2 = jt * 16 + kg * 4 + reg;
            if (j2 != i) {
                vsum0 += fast_tanh(a[jt][0][reg]);
                vsum1 += fast_tanh(a[jt][1][reg]);
            }
        }
    }
    vsum0 += __shfl_xor(vsum0, 16); vsum0 += __shfl_xor(vsum0, 32);
    vsum1 += __shfl_xor(vsum1, 16); vsum1 += __shfl_xor(vsum1, 32);
    if (lane < 16) {
        float* Xp = X + (size_t)bi_ * NBB + wave * 32 + lane;
        if (FIRST) {
            const float* er = W_emb + (size_t)zi * NBB + wave * 32 + lane;
            Xp[0]  = er[0]  + vsum0;
            Xp[16] = er[16] + vsum1;
        } else {
            Xp[0]  += vsum0;
            Xp[16] += vsum1;
        }
    }
}

// ---------------- fused fallback (old layouts) ----------------
__global__ __launch_bounds__(256, 3) void interact_fused(
    const int* __restrict__ Z, const float* __restrict__ C,
    const _Float16* __restrict__ WcT, const float* __restrict__ bc,
    const _Float16* __restrict__ WfT, const _Float16* __restrict__ fXF,
    float* __restrict__ X)
{
    __shared__ __align__(16) _Float16 Cs[NN * KPAD];
    __shared__ __align__(16) _Float16 fVs[NN * NFF];

    const int bi_ = blockIdx.x;
    const int b = bi_ >> 6, i = bi_ & 63;
    if (Z[b * NN + i] == 0) return;

    const int t = threadIdx.x;
    const int wave = t >> 6, lane = t & 63;
    const int l15 = lane & 15, kg = lane >> 4;

    stage_C(C + (size_t)bi_ * NN * NGG, Cs, t);

    f16x8 aw[4][4];
    float4 bcq[4];
    #pragma unroll
    for (int ct = 0; ct < 4; ++ct) {
        #pragma unroll
        for (int ks = 0; ks < 4; ++ks)
            aw[ct][ks] = *(const f16x8*)&WcT[(size_t)(wave * 64 + ct * 16 + l15) * KPAD + ks * 32 + kg * 8];
        bcq[ct] = *(const float4*)&bc[wave * 64 + ct * 16 + kg * 4];
    }
    __syncthreads();

    #pragma unroll
    for (int jt = 0; jt < 4; ++jt) {
        const int j = jt * 16 + l15;
        const int sw = (l15 & 7) << 3;
        f16x8 bfr[4];
        #pragma unroll
        for (int ks = 0; ks < 4; ++ks)
            bfr[ks] = *(const f16x8*)&Cs[j * KPAD + ((ks * 32 + kg * 8) ^ sw)];
        #pragma unroll
        for (int ct = 0; ct < 4; ++ct) {
            f32x4 acc = {bcq[ct].x, bcq[ct].y, bcq[ct].z, bcq[ct].w};
            #pragma unroll
            for (int ks = 0; ks < 4; ++ks)
                acc = __builtin_amdgcn_mfma_f32_16x16x32_f16(aw[ct][ks], bfr[ks], acc, 0, 0, 0);
            const int u = ct * 16 + kg * 4;
            const int ksf = wave * 2 + (u >> 5);
            const int kgf = (u >> 3) & 3;
            const int e0 = u & 4;
            f16x4 fx4 = *(const f16x4*)&fXF[((size_t)(b * 32 + jt * 8 + ksf) * 64 + (kgf * 16 + l15)) * 8 + e0];
            const int f0 = wave * 64 + u;
            f16x4 o;
            o[0] = (_Float16)(acc[0] * (float)fx4[0]);
            o[1] = (_Float16)(acc[1] * (float)fx4[1]);
            o[2] = (_Float16)(acc[2] * (float)fx4[2]);
            o[3] = (_Float16)(acc[3] * (float)fx4[3]);
            *(f16x4*)&fVs[j * NFF + (f0 ^ ((j & 7) << 3))] = o;
        }
    }
    __syncthreads();

    f16x8 bwf[2][8];
    #pragma unroll
    for (int ct = 0; ct < 2; ++ct)
        #pragma unroll
        for (int ks = 0; ks < 8; ++ks)
            bwf[ct][ks] = *(const f16x8*)&WfT[(size_t)(wave * 32 + ct * 16 + l15) * NFF + ks * 32 + kg * 8];

    float vsum0 = 0.f, vsum1 = 0.f;
    #pragma unroll
    for (int jt = 0; jt < 4; ++jt) {
        const int r = jt * 16 + l15;
        const int sw = (l15 & 7) << 3;
        f32x4 a0 = {0.f, 0.f, 0.f, 0.f}, a1 = {0.f, 0.f, 0.f, 0.f};
        #pragma unroll
        for (int ks = 0; ks < 8; ++ks) {
            f16x8 av = *(const f16x8*)&fVs[r * NFF + ((ks * 32 + kg * 8) ^ sw)];
            a0 = __builtin_amdgcn_mfma_f32_16x16x32_f16(av, bwf[0][ks], a0, 0, 0, 0);
            a1 = __builtin_amdgcn_mfma_f32_16x16x32_f16(av, bwf[1][ks], a1, 0, 0, 0);
        }
        #pragma unroll
        for (int reg = 0; reg < 4; ++reg) {
            int j2 = jt * 16 + kg * 4 + reg;
            if (j2 != i) {
                vsum0 += fast_tanh(a0[reg]);
                vsum1 += fast_tanh(a1[reg]);
            }
        }
    }
    vsum0 += __shfl_xor(vsum0, 16); vsum0 += __shfl_xor(vsum0, 32);
    vsum1 += __shfl_xor(vsum1, 16); vsum1 += __shfl_xor(vsum1, 32);
    if (lane < 16) {
        float* Xp = X + (size_t)bi_ * NBB + wave * 32 + lane;
        Xp[0]  += vsum0;
        Xp[16] += vsum1;
    }
}

// ---------------- readout (MFMA, one block per b, writes y directly) ----------------
// Dead rows of X may hold garbage: each j is an isolated MFMA output COLUMN,
// masked on Z[j]>0 before the sum — no contamination.
__global__ __launch_bounds__(256) void readout_kernel(
    const int* __restrict__ Z, const float* __restrict__ X,
    const _Float16* __restrict__ W1F, const float* __restrict__ b1,
    const float* __restrict__ W2, const float* __restrict__ b2,
    float* __restrict__ y)
{
    __shared__ __align__(16) _Float16 Xs[NN * KPAD];   // 16 KB
    __shared__ float part[4][NN];                      // 1 KB
    const int b = blockIdx.x, t = threadIdx.x;
    const int wave = t >> 6, lane = t & 63;
    const int l15 = lane & 15, kg = lane >> 4;

    stage_Xrow<0>(X, Z, (const float*)nullptr, b, Xs, t);

    f16x8 aw[4];
    #pragma unroll
    for (int ks = 0; ks < 4; ++ks)
        aw[ks] = *(const f16x8*)&W1F[(size_t)((wave * 4 + ks) * 64 + lane) * 8];
    float4 b1q = *(const float4*)&b1[wave * 16 + kg * 4];
    float4 w2q = *(const float4*)&W2[wave * 16 + kg * 4];
    __syncthreads();

    f32x4 acc[4];
    #pragma unroll
    for (int jt = 0; jt < 4; ++jt) acc[jt] = (f32x4){b1q.x, b1q.y, b1q.z, b1q.w};

    #pragma unroll
    for (int ks = 0; ks < 4; ++ks) {
        #pragma unroll
        for (int jt = 0; jt < 4; ++jt) {
            const int j = jt * 16 + l15;
            const int sw = (l15 & 7) << 3;
            f16x8 bfr = *(const f16x8*)&Xs[j * KPAD + ((ks * 32 + kg * 8) ^ sw)];
            acc[jt] = __builtin_amdgcn_mfma_f32_16x16x32_f16(aw[ks], bfr, acc[jt], 0, 0, 0);
        }
    }

    #pragma unroll
    for (int jt = 0; jt < 4; ++jt) {
        float s = fast_tanh(acc[jt][0]) * w2q.x + fast_tanh(acc[jt][1]) * w2q.y
                + fast_tanh(acc[jt][2]) * w2q.z + fast_tanh(acc[jt][3]) * w2q.w;
        s += __shfl_xor(s, 16); s += __shfl_xor(s, 32);
        if (lane < 16) part[wave][jt * 16 + lane] = s;
    }
    __syncthreads();

    if (t < NN) {
        float s = part[0][t] + part[1][t] + part[2][t] + part[3][t] + b2[0];
        float v = (Z[b * NN + t] > 0) ? s : 0.f;
        #pragma unroll
        for (int off = 32; off > 0; off >>= 1) v += __shfl_down(v, off);
        if (t == 0) y[b] = v;
    }
}

extern "C" void kernel_launch(void* const* d_in, const int* in_sizes, int n_in,
                              void* d_out, int out_size, void* d_ws, size_t ws_size,
                              hipStream_t stream) {
    (void)in_sizes; (void)n_in; (void)out_size;
    const int*   Z    = (const int*)d_in[0];
    const float* C    = (const float*)d_in[1];
    const float* Wemb = (const float*)d_in[2];
    const float* Wc   = (const float*)d_in[3];
    const float* bc   = (const float*)d_in[4];
    const float* Wi   = (const float*)d_in[5];
    const float* bi   = (const float*)d_in[6];
    const float* Wf   = (const float*)d_in[7];
    const float* W1   = (const float*)d_in[8];
    const float* b1   = (const float*)d_in[9];
    const float* W2   = (const float*)d_in[10];
    const float* b2   = (const float*)d_in[11];
    float* y = (float*)d_out;

    // ws: X f32 | fXF | WcF | WfF | WiF | W1F | WcT | WfT | fCF(67MB)
    char* p = (char*)d_ws;
    float*    X    = (float*)p;      p += (size_t)BB * NN * NBB * 4;
    _Float16* fXF  = (_Float16*)p;   p += (size_t)BB * NN * NFF * 2;
    _Float16* WcF  = (_Float16*)p;   p += (size_t)WCF_N * 2;
    _Float16* WfF  = (_Float16*)p;   p += (size_t)WFF_N * 2;
    _Float16* WiF  = (_Float16*)p;   p += (size_t)WIF_N * 2;
    _Float16* W1F  = (_Float16*)p;   p += (size_t)W1F_N * 2;
    _Float16* WcT  = (_Float16*)p;   p += (size_t)NFF * KPAD * 2;
    _Float16* WfT  = (_Float16*)p;   p += (size_t)NBB * NFF * 2;
    size_t base = (size_t)(p - (char*)d_ws);
    size_t fcf_bytes = (size_t)BB * NN * NN * NFF * 2;   // 67 MB
    bool split = (ws_size >= base + fcf_bytes);          // constant per session
    _Float16* fCF = (_Float16*)p;

    prep_kernel<<<PREP_GRID, 256, 0, stream>>>(Wc, Wf, Wi, W1, WcF, WfF, WiF, W1F);

    if (split) {
        // pass-1 inputs: fc + fx(embed-fused) merged
        fcfx_kernel<<<FXM_GRID + BB * NN, 256, 0, stream>>>(Z, C, WcF, bc, fCF, WiF, bi, Wemb, fXF);
        interact_lite<1><<<BB * NN, 256, 0, stream>>>(Z, fCF, WfF, fXF, X, Wemb);
        fxm_kernel<<<FXM_GRID, 256, 0, stream>>>(X, WiF, bi, Z, fXF);
        interact_lite<0><<<BB * NN, 256, 0, stream>>>(Z, fCF, WfF, fXF, X, Wemb);
        fxm_kernel<<<FXM_GRID, 256, 0, stream>>>(X, WiF, bi, Z, fXF);
        interact_lite<0><<<BB * NN, 256, 0, stream>>>(Z, fCF, WfF, fXF, X, Wemb);
    } else {
        embed_kernel<<<BB * NN, NBB, 0, stream>>>(Z, Wemb, X);
        transpose_pad_kernel<<<(NFF * KPAD) / 256, 256, 0, stream>>>(Wc, WcT, NGG, KPAD, NFF);
        transpose_pad_kernel<<<(NBB * NFF) / 256, 256, 0, stream>>>(Wf, WfT, NFF, NFF, NBB);
        for (int it = 0; it < NITER; ++it) {
            fxm_kernel<<<FXM_GRID, 256, 0, stream>>>(X, WiF, bi, Z, fXF);
            interact_fused<<<BB * NN, 256, 0, stream>>>(Z, C, WcT, bc, WfT, fXF, X);
        }
    }
    readout_kernel<<<BB, 256, 0, stream>>>(Z, X, W1F, b1, W2, b2, y);
}